// Round 10
// baseline (3947.589 us; speedup 1.0000x reference)
//
#include <hip/hip_runtime.h>
#include <stdint.h>

// ---------------------------------------------------------------------------
// RNN speech decoder. R14:
//  * R13 analysis (active-CU scaling of counters): step ~7000cy = MFMA wall
//    ~1300 + VALU wall ~2400(busy)/~1200(wall) + exchange latency ~1800 +
//    skew. Latency is at its L3 floor; the compute walls are per-CU.
//  * R14: j-split 8 -> 16. 32 blocks x 512 thr (16 j x 2 dir), each owns
//    32 h-cols. Per-wave MFMA 48->24 (waves = kt x ntgrp x Mtile), act
//    4->2 cols/thread, exchange word 8B->4B (15 partners, same bytes,
//    still one batched latency). Weights stay 96 VGPR/lane; total ~180
//    (VGPR=64 in counters would mean spill). LDS ~90KB.
//  * Protocol byte-identical to R13 (poison payload, batched retry,
//    publish-first). GEMM stack / decoder / day path unchanged.
// ---------------------------------------------------------------------------

#define T_SEQ 2048
#define G3    1536
#define GS    3072   // fused gate width (fwd | bwd)
#define HW    256    // packed bf16 words per h vector
#define CLEN  64
#define WARM  64
#define NCH   32     // chunks per dir
#define NST   128    // steps per scan (CLEN+WARM)

typedef __attribute__((ext_vector_type(8))) short short8;
typedef __attribute__((ext_vector_type(4))) float f32x4;

__device__ inline unsigned int pack_bf16(float a, float b){
  unsigned int ua = __float_as_uint(a); ua = (ua + 0x7FFFu + ((ua>>16)&1u)) >> 16;
  unsigned int ub = __float_as_uint(b); ub = (ub + 0x7FFFu + ((ub>>16)&1u)) >> 16;
  return (ub<<16) | (ua & 0xFFFFu);
}
__device__ inline float bf2f(unsigned int h){ return __uint_as_float(h<<16); }

#define GBN 128
#define GBK 64
#define LSTR 36

// ---------------------------------------------------------------------------
// Day GEMM: C = softsign(x @ dayWT + bsel) -> bf16 hpadb rows 31..8222.
// ---------------------------------------------------------------------------
__global__ __launch_bounds__(256)
void day_gemm(const float* __restrict__ A, const unsigned int* __restrict__ Bpk,
              const float* __restrict__ bias, unsigned short* __restrict__ Cb)
{
  __shared__ __align__(16) unsigned int aL[128*LSTR];
  __shared__ __align__(16) unsigned int bL[GBN*LSTR];
  const int tid = threadIdx.x;
  const int m0 = blockIdx.x * 128;
  const int n0 = blockIdx.y * GBN;
  const int lane = tid & 63;
  const int w = tid >> 6;
  const int wm = (w & 1) * 64;
  const int wn = (w >> 1) * 64;
  const int ln = lane & 15;
  const int q  = lane >> 4;
  const int K = 512;

  f32x4 acc[4][4];
#pragma unroll
  for (int i=0;i<4;i++)
#pragma unroll
    for (int j=0;j<4;j++) acc[i][j] = (f32x4)0.f;

  const int ar = tid >> 1, ah = tid & 1;
  const int br = tid >> 1, bh = tid & 1;

  for (int kt = 0; kt < K/GBK; kt++){
    {
      const float* ap = A + (size_t)(m0+ar)*K + kt*GBK + ah*32;
      float4 av[8];
#pragma unroll
      for (int g=0; g<8; g++) av[g] = ((const float4*)ap)[g];
#pragma unroll
      for (int g=0; g<8; g++){
        aL[ar*LSTR + ah*16 + g*2    ] = pack_bf16(av[g].x, av[g].y);
        aL[ar*LSTR + ah*16 + g*2 + 1] = pack_bf16(av[g].z, av[g].w);
      }
    }
    {
      const unsigned int* bp = Bpk + (size_t)(n0+br)*(K>>1) + kt*32 + bh*16;
#pragma unroll
      for (int g=0; g<4; g++)
        *((uint4*)&bL[br*LSTR + bh*16 + g*4]) = ((const uint4*)bp)[g];
    }
    __syncthreads();
#pragma unroll
    for (int ks=0; ks<2; ks++){
      short8 af[4], bf[4];
#pragma unroll
      for (int i=0;i<4;i++){
        uint4 u = *(const uint4*)&aL[(wm + i*16 + ln)*LSTR + ks*16 + q*4];
        af[i] = *(const short8*)&u;
      }
#pragma unroll
      for (int j=0;j<4;j++){
        uint4 u = *(const uint4*)&bL[(wn + j*16 + ln)*LSTR + ks*16 + q*4];
        bf[j] = *(const short8*)&u;
      }
#pragma unroll
      for (int i=0;i<4;i++)
#pragma unroll
        for (int j=0;j<4;j++)
          acc[i][j] = __builtin_amdgcn_mfma_f32_16x16x32_bf16(af[i], bf[j], acc[i][j], 0,0,0);
    }
    __syncthreads();
  }
#pragma unroll
  for (int i=0;i<4;i++)
#pragma unroll
    for (int j=0;j<4;j++){
      int n = n0 + wn + j*16 + ln;
      float bs = bias[n];
#pragma unroll
      for (int r=0;r<4;r++){
        int m = m0 + wm + i*16 + q*4 + r;
        float v = acc[i][j][r] + bs;
        v = v / (1.f + fabsf(v));
        Cb[(size_t)(m+31)*512 + n] = (unsigned short)(pack_bf16(v, v) & 0xFFFFu);
      }
    }
}

// ---------------------------------------------------------------------------
// Input-gate GEMM, bf16 A (unchanged).
// ---------------------------------------------------------------------------
template<int BM, int AM>
__global__ __launch_bounds__(256)
void gemm_bt(const unsigned short* __restrict__ Abf,
             const unsigned int* __restrict__ A1, const unsigned int* __restrict__ A2,
             const unsigned int* __restrict__ Bpk,
             const float* __restrict__ biasF, const float* __restrict__ biasB,
             float* __restrict__ C, int K, int ldc)
{
  constexpr int AI = BM/32;
  __shared__ __align__(16) unsigned int aL[BM*LSTR];
  __shared__ __align__(16) unsigned int bL[GBN*LSTR];
  const int tid = threadIdx.x;
  const int m0 = blockIdx.x * BM;
  const int n0 = blockIdx.y * GBN;
  const int lane = tid & 63;
  const int w = tid >> 6;
  const int wm = (w & 1) * (BM/2);
  const int wn = (w >> 1) * 64;
  const int ln = lane & 15;
  const int q  = lane >> 4;

  f32x4 acc[AI][4];
#pragma unroll
  for (int i=0;i<AI;i++)
#pragma unroll
    for (int j=0;j<4;j++) acc[i][j] = (f32x4)0.f;

  const int ldKw = K >> 1;
  const int br = tid >> 1, bh = tid & 1;

  for (int kt = 0; kt < K/GBK; kt++){
    if (AM == 1){
      const int ar = tid >> 2, ah = tid & 3;
      const int row = (m0+ar)*4 + (kt>>3);
      const uint4* ap = (const uint4*)(Abf + (size_t)row*512 + (kt&7)*64 + ah*16);
      *((uint4*)&aL[ar*LSTR + ah*8    ]) = ap[0];
      *((uint4*)&aL[ar*LSTR + ah*8 + 4]) = ap[1];
    } else {
      const int ar = tid >> 1, ah = tid & 1;
      const int k0 = kt*GBK;
      const unsigned int* ub = ((k0 < 512) ? A1 : A2)
                               + (size_t)(m0+ar)*HW + ((k0 & 511) >> 1) + ah*16;
#pragma unroll
      for (int g=0; g<4; g++)
        *((uint4*)&aL[ar*LSTR + ah*16 + g*4]) = ((const uint4*)ub)[g];
    }
    {
      const unsigned int* bp = Bpk + (size_t)(n0+br)*ldKw + kt*32 + bh*16;
#pragma unroll
      for (int g=0; g<4; g++)
        *((uint4*)&bL[br*LSTR + bh*16 + g*4]) = ((const uint4*)bp)[g];
    }
    __syncthreads();
#pragma unroll
    for (int ks=0; ks<2; ks++){
      short8 af[AI], bf[4];
#pragma unroll
      for (int i=0;i<AI;i++){
        uint4 u = *(const uint4*)&aL[(wm + i*16 + ln)*LSTR + ks*16 + q*4];
        af[i] = *(const short8*)&u;
      }
#pragma unroll
      for (int j=0;j<4;j++){
        uint4 u = *(const uint4*)&bL[(wn + j*16 + ln)*LSTR + ks*16 + q*4];
        bf[j] = *(const short8*)&u;
      }
#pragma unroll
      for (int i=0;i<AI;i++)
#pragma unroll
        for (int j=0;j<4;j++)
          acc[i][j] = __builtin_amdgcn_mfma_f32_16x16x32_bf16(af[i], bf[j], acc[i][j], 0,0,0);
    }
    __syncthreads();
  }
#pragma unroll
  for (int i=0;i<AI;i++)
#pragma unroll
    for (int j=0;j<4;j++){
      int n = n0 + wn + j*16 + ln;
      float bs = (n < 1536) ? biasF[n] : biasB[n-1536];
#pragma unroll
      for (int r=0;r<4;r++){
        int m = m0 + wm + i*16 + q*4 + r;
        C[(size_t)m*ldc + n] = acc[i][j][r] + bs;
      }
    }
}

// ---------------------------------------------------------------------------
// scan2 (R14): M-batched MFMA GRU scan, j-split 16.
// Grid 32 x 512thr. dir = bid&1, j = bid>>1 (32-col slice [32j,32j+32)).
// Waves: kt = w>>2 (K-half), wn = (w>>1)&1 (3 nt tiles), wm = w&1 (M-tile).
// Weights: 24 frags (3nt x 8kkl) = 96 VGPR/lane. Gates per block: 96 cols
// (r|z|n x 32). Exchange: 4B words, 15 partners, poison protocol with
// batched retry (R13). hA parity double-buffer, 2 barriers (proven R9).
// ---------------------------------------------------------------------------
__global__ __launch_bounds__(512)
void scan2_kernel(const float* __restrict__ gi,
                  const uint4* __restrict__ wqF, const uint4* __restrict__ wqB,
                  const float* __restrict__ bhnF, const float* __restrict__ bhnB,
                  unsigned int* __restrict__ hbF, unsigned int* __restrict__ hbB,
                  unsigned int* __restrict__ exch)
{
  const int bid = blockIdx.x;
  const int dir = bid & 1;
  const int j   = bid >> 1;        // 0..15
  const int tid = threadIdx.x;
  const int w    = tid >> 6;
  const int lane = tid & 63;
  const int ln = lane & 15, q = lane >> 4;
  const int kt = w >> 2;           // K-half (rows kt*256..+255)
  const int wn = (w >> 1) & 1;     // nt group (tiles wn*3..wn*3+2)
  const int wm = w & 1;            // M-tile (chunks wm*16..+15)
  const unsigned int POI = 0xAAAAAAAAu;

  const float* gi_d = gi + dir*1536;
  const uint4* wq = dir ? wqB : wqF;
  const float* bhn = dir ? bhnB : bhnF;
  unsigned int* hb = dir ? hbB : hbF;
  unsigned int* exd = exch + (size_t)dir*16*NST*512;

  // ---- weights: 24 frags/lane (3 nt x 8 kk-local)
  short8 w8[3][8];
  {
    const uint4* wb = wq + (size_t)j*6*16*64;
#pragma unroll
    for (int nt=0; nt<3; nt++)
#pragma unroll
      for (int kkl=0; kkl<8; kkl++){
        uint4 u = wb[(size_t)(((wn*3+nt)*16) + (kt*8+kkl))*64 + lane];
        w8[nt][kkl] = *(const short8*)&u;
      }
  }

  __shared__ __align__(16) unsigned short hA[2][NCH][512];
  __shared__ __align__(16) float gL[2][NCH][100];   // 96 gate cols + pad

  const int m  = tid >> 4;   // chunk 0..31
  const int cp = tid & 15;
  const int c0 = 2*cp;       // 2 cols/thread within the 32-col slice
  float2 bh2 = *(const float2*)&bhn[j*32 + c0];
  float hp0=0.f, hp1=0.f;

  {
    uint4 zz; zz.x=0u; zz.y=0u; zz.z=0u; zz.w=0u;
    uint4* zp = (uint4*)&hA[0][0][0];
    for (int i2 = tid; i2 < 4096; i2 += 512) zp[i2] = zz;
  }
  __syncthreads();

  for (int idx = 0; idx < NST; idx++){
    const int p = idx & 1;
    // gi prefetch (validity-clamped address)
    int t = dir ? (64*m + 127 - idx) : (64*m - 64 + idx);
    const bool valid = (t >= 0) && (t < T_SEQ);
    int tc = t < 0 ? 0 : (t > T_SEQ-1 ? T_SEQ-1 : t);
    const float* gb = gi_d + (size_t)tc*GS + j*32 + c0;
    float2 g_r = *(const float2*)(gb);
    float2 g_z = *(const float2*)(gb + 512);
    float2 g_n = *(const float2*)(gb + 1024);

    if (idx > 0){
      // initial batch: 15 loads in flight (poison-in-payload)
      unsigned int v[15];
#pragma unroll
      for (int rb = 0; rb < 15; rb++){
        int jp = (j + 1 + rb) & 15;
        v[rb] = __hip_atomic_load(&exd[((size_t)jp*NST + (idx-1))*512 + tid],
                                  __ATOMIC_RELAXED, __HIP_MEMORY_SCOPE_AGENT);
      }
      // batched retry: all 15 reloaded per round, then merged (R13 pattern)
      for (;;){
        bool bad = false;
#pragma unroll
        for (int rb = 0; rb < 15; rb++)
          if (v[rb] == POI) bad = true;
        if (!bad) break;
        unsigned int nv[15];
#pragma unroll
        for (int rb = 0; rb < 15; rb++){
          int jp = (j + 1 + rb) & 15;
          nv[rb] = __hip_atomic_load(&exd[((size_t)jp*NST + (idx-1))*512 + tid],
                                     __ATOMIC_RELAXED, __HIP_MEMORY_SCOPE_AGENT);
        }
#pragma unroll
        for (int rb = 0; rb < 15; rb++)
          if (v[rb] == POI) v[rb] = nv[rb];
      }
#pragma unroll
      for (int rb = 0; rb < 15; rb++){
        int jp = (j + 1 + rb) & 15;
        int uo = (m*512 + jp*32 + c0) ^ ((m&7)<<3);
        ((unsigned int*)&hA[p][0][0])[uo>>1] = v[rb];
      }
    }
    __syncthreads();                       // B1

    // ---- MFMA: H-tile wm x 96 gate cols, K-half kt
    f32x4 ac[3];
#pragma unroll
    for (int nt=0; nt<3; nt++) ac[nt] = (f32x4)0.f;
    const unsigned short* hbp = &hA[p][0][0];
#pragma unroll
    for (int kkl=0; kkl<8; kkl++){
      int kb = (kt*8 + kkl)*32 + q*8;
      int row = wm*16 + ln;
      int ua = (row*512 + kb) ^ ((row&7)<<3);
      short8 af = *(const short8*)&hbp[ua];
#pragma unroll
      for (int nt=0; nt<3; nt++)
        ac[nt] = __builtin_amdgcn_mfma_f32_16x16x32_bf16(af, w8[nt][kkl], ac[nt], 0,0,0);
    }
#pragma unroll
    for (int nt=0; nt<3; nt++){
      int ncol = (wn*3+nt)*16 + ln;
      float* gw = &gL[kt][0][0];
#pragma unroll
      for (int r=0; r<4; r++)
        gw[(wm*16 + 4*q + r)*100 + ncol] = ac[nt][r];
    }
    __syncthreads();                       // B2

    // ---- activation: thread = (chunk m, cols c0..c0+1)
    const float* g0 = &gL[0][m][0];
    const float* g1 = &gL[1][m][0];
    float2 xr0 = *(const float2*)&g0[c0],    xr1 = *(const float2*)&g1[c0];
    float2 xz0 = *(const float2*)&g0[32+c0], xz1 = *(const float2*)&g1[32+c0];
    float2 xn0 = *(const float2*)&g0[64+c0], xn1 = *(const float2*)&g1[64+c0];

    float h0,h1;
    {
      float ar = xr0.x + xr1.x, az = xz0.x + xz1.x, an = xn0.x + xn1.x;
      float r = __fdividef(1.f, 1.f + __expf(-(g_r.x + ar)));
      float z = __fdividef(1.f, 1.f + __expf(-(g_z.x + az)));
      float e = __expf(2.f*(g_n.x + r*(an + bh2.x)));
      float n = 1.f - __fdividef(2.f, e + 1.f);
      h0 = (1.f - z)*n + z*hp0; h0 = valid ? h0 : 0.f; hp0 = h0;
    }
    {
      float ar = xr0.y + xr1.y, az = xz0.y + xz1.y, an = xn0.y + xn1.y;
      float r = __fdividef(1.f, 1.f + __expf(-(g_r.y + ar)));
      float z = __fdividef(1.f, 1.f + __expf(-(g_z.y + az)));
      float e = __expf(2.f*(g_n.y + r*(an + bh2.y)));
      float n = 1.f - __fdividef(2.f, e + 1.f);
      h1 = (1.f - z)*n + z*hp1; h1 = valid ? h1 : 0.f; hp1 = h1;
    }

    unsigned int pv = pack_bf16(h0, h1);
    if (pv == POI) pv ^= 1u;               // poison collision: 1-ulp flip
    // publish FIRST (earliest L3 visibility), then local LDS + hb
    __hip_atomic_store(&exd[((size_t)j*NST + idx)*512 + tid], pv,
                       __ATOMIC_RELAXED, __HIP_MEMORY_SCOPE_AGENT);
    int uo = (m*512 + j*32 + c0) ^ ((m&7)<<3);
    ((unsigned int*)&hA[p^1][0][0])[uo>>1] = pv;
    if (idx >= WARM)
      hb[(size_t)t*HW + j*16 + cp] = pv;
    // no 3rd barrier: parity dbuf keeps LDS writes disjoint (see R9).
  }
}

// ---------------------------------------------------------------------------
// Decoder: logits = [hf|hb](packed bf16) @ Wdec + bdec, row log_softmax.
// ---------------------------------------------------------------------------
__global__ __launch_bounds__(64)
void decoder_kernel(const unsigned int* __restrict__ hf, const unsigned int* __restrict__ hbk,
                    const float* __restrict__ Wd, const float* __restrict__ bd,
                    float* __restrict__ out)
{
  const int t = blockIdx.x;
  const int lane = threadIdx.x;
  __shared__ float y[1024];
  for (int i = lane; i < HW; i += 64){
    unsigned int uf = hf [(size_t)t*HW + i];
    unsigned int ub = hbk[(size_t)t*HW + i];
    y[2*i]       = bf2f(uf & 0xFFFFu); y[2*i+1]       = bf2f(uf >> 16);
    y[512 + 2*i] = bf2f(ub & 0xFFFFu); y[512 + 2*i+1] = bf2f(ub >> 16);
  }
  __syncthreads();
  float v = -1e30f;
  if (lane < 41){
    float acc = bd[lane];
    for (int k=0;k<1024;k++) acc += y[k] * Wd[(size_t)k*41 + lane];
    v = acc;
  }
  float m = v;
#pragma unroll
  for (int off=32; off; off>>=1) m = fmaxf(m, __shfl_xor(m, off, 64));
  float e = (lane < 41) ? __expf(v - m) : 0.f;
  float ssum = e;
#pragma unroll
  for (int off=32; off; off>>=1) ssum += __shfl_xor(ssum, off, 64);
  if (lane < 41) out[(size_t)t*41 + lane] = (v - m) - __logf(ssum);
}

// ---------------------------------------------------------------------------
// Prep kernels
// ---------------------------------------------------------------------------
__global__ void poison_kernel(unsigned int* p, long n){
  long i = (long)blockIdx.x*blockDim.x + threadIdx.x;
  long st = (long)gridDim.x*blockDim.x;
  for (; i < n; i += st) p[i] = 0xAAAAAAAAu;
}
__global__ void zero_u_kernel(unsigned int* p, int n){
  int i = blockIdx.x*blockDim.x + threadIdx.x;
  if (i < n) p[i] = 0u;
}
// day weights: packed word[n][k2] = pack(dayW[d][n][2k2], dayW[d][n][2k2+1])
__global__ void daysel_kernel(const float* __restrict__ dw, const float* __restrict__ db,
                              const int* __restrict__ didx, unsigned int* __restrict__ wtpk,
                              float* __restrict__ bsel){
  int d = *didx;
  int i = blockIdx.x*256 + threadIdx.x;
  if (i < 512*256){
    int n = i >> 8, k2 = i & 255;
    const float* s = dw + (size_t)d*262144 + (size_t)n*512 + 2*k2;
    wtpk[i] = pack_bf16(s[0], s[1]);
  }
  if (i < 512) bsel[i] = db[(size_t)d*512 + i];
}
// Transpose-pack fp32 B [K][ldb] column slice -> pair-words dst[n][K/2].
__global__ __launch_bounds__(256)
void packB_kernel(const float* __restrict__ src, int ldb,
                  unsigned int* __restrict__ dst, int K)
{
  __shared__ float tile[64][65];
  const int k0 = blockIdx.x * 64;
  const int n0 = blockIdx.y * 64;
  const int tid = threadIdx.x;
#pragma unroll
  for (int g=0; g<16; g++){
    int idx = g*256 + tid;
    int kr = idx >> 6, nc = idx & 63;
    tile[kr][nc] = src[(size_t)(k0+kr)*ldb + n0 + nc];
  }
  __syncthreads();
  const int ldKw = K >> 1;
#pragma unroll
  for (int g=0; g<8; g++){
    int wi = g*256 + tid;
    int nl = wi >> 5, k2 = wi & 31;
    dst[(size_t)(n0+nl)*ldKw + (k0>>1) + k2] = pack_bf16(tile[2*k2][nl], tile[2*k2+1][nl]);
  }
}
// Wh frag-pack for scan2 j16: dst[(((ld*16+j)*6+nt)*16+kk)*64+lane] = uint4
// of 8 bf16: col_local = nt*16+(lane&15) in [0,96); g = col_local>>5,
// c = col_local&31; gcol = g*512 + j*32 + c; kb = kk*32 + (lane>>4)*8;
// words e: pack(W[kb+2e][gcol], W[kb+2e+1][gcol]).
struct WhPtrs { const float* p[10]; };
__global__ void whfrag_kernel(WhPtrs wps, uint4* __restrict__ dst){
  int i = blockIdx.x*256 + threadIdx.x;
  if (i >= 983040) return;
  int ld = i / 98304;
  int r  = i % 98304;
  int lane = r & 63;
  int kk = (r >> 6) & 15;
  int t2 = r >> 10;          // 0..95
  int nt = t2 % 6;
  int j  = t2 / 6;           // 0..15
  int cl = nt*16 + (lane & 15);
  int g = cl >> 5, c = cl & 31;
  int gcol = g*512 + j*32 + c;
  int kb = kk*32 + (lane >> 4)*8;
  const float* W = wps.p[ld];
  unsigned int wd[4];
#pragma unroll
  for (int e=0; e<4; e++)
    wd[e] = pack_bf16(W[(size_t)(kb + 2*e)*G3 + gcol],
                      W[(size_t)(kb + 2*e + 1)*G3 + gcol]);
  uint4 o; o.x = wd[0]; o.y = wd[1]; o.z = wd[2]; o.w = wd[3];
  dst[i] = o;
}

// ---------------------------------------------------------------------------
extern "C" void kernel_launch(void* const* d_in, const int* in_sizes, int n_in,
                              void* d_out, int out_size, void* d_ws, size_t ws_size,
                              hipStream_t stream)
{
  const float* x     = (const float*)d_in[0];
  const int*   didx  = (const int*)  d_in[1];
  const float* dayW  = (const float*)d_in[2];
  const float* dayB  = (const float*)d_in[3];
  const float* Wi0f  = (const float*)d_in[4];
  const float* bi0f  = (const float*)d_in[5];
  const float* Wh0f  = (const float*)d_in[6];
  const float* bhn0f = (const float*)d_in[7];
  const float* Wi0b  = (const float*)d_in[8];
  const float* bi0b  = (const float*)d_in[9];
  const float* Wh0b  = (const float*)d_in[10];
  const float* bhn0b = (const float*)d_in[11];
  const float* WiRf  = (const float*)d_in[12];
  const float* biRf  = (const float*)d_in[13];
  const float* WhRf  = (const float*)d_in[14];
  const float* bhnRf = (const float*)d_in[15];
  const float* WiRb  = (const float*)d_in[16];
  const float* biRb  = (const float*)d_in[17];
  const float* WhRb  = (const float*)d_in[18];
  const float* bhnRb = (const float*)d_in[19];
  const float* Wdec  = (const float*)d_in[20];
  const float* bdec  = (const float*)d_in[21];
  float* out = (float*)d_out;

  char* ws = (char*)d_ws;
  size_t off = 0;
  unsigned int* hbuf[5][2];
  for (int l=0;l<5;l++) for (int d=0;d<2;d++){
    hbuf[l][d] = (unsigned int*)(ws+off); off += (size_t)T_SEQ*HW*4;
  }
  float* gi   = (float*)(ws+off); off += (size_t)T_SEQ*GS*4;             // 25.2 MB
  unsigned short* hpadb = (unsigned short*)(ws+off); off += ((size_t)8223*512*2 + 255) & ~255ull;
  unsigned int* wtpk = (unsigned int*)(ws+off); off += (size_t)512*256*4;
  float* bsel = (float*)(ws+off); off += 2048;
  uint4* whq = (uint4*)(ws+off); off += (size_t)983040*16;               // 15.7 MB
  unsigned int* exch = (unsigned int*)(ws+off); off += (size_t)2*16*NST*512*4;  // 8.4 MB
  unsigned int* bpk0 = (unsigned int*)(ws+off); off += (size_t)3072*8192*4;   // 100.7 MB
  unsigned int* bpkR = (unsigned int*)(ws+off); off += (size_t)4*3072*512*4;  // 25.2 MB
  // total ~204 MB

  const long EXNW = (long)2*16*NST*512;   // exch in u32 words

  // --- prep
  hipLaunchKernelGGL(poison_kernel, dim3(1024), dim3(256), 0, stream,
                     exch, EXNW);
  hipLaunchKernelGGL(zero_u_kernel, dim3((7936+255)/256), dim3(256), 0, stream,
                     (unsigned int*)hpadb, 7936);  // rows 0..30 bf16 zeros
  hipLaunchKernelGGL(daysel_kernel, dim3(512), dim3(256), 0, stream,
                     dayW, dayB, didx, wtpk, bsel);
  WhPtrs wps;
  wps.p[0] = Wh0f; wps.p[1] = Wh0b;
  for (int l=0;l<4;l++){
    wps.p[2+2*l] = WhRf + (size_t)l*512*1536;
    wps.p[3+2*l] = WhRb + (size_t)l*512*1536;
  }
  hipLaunchKernelGGL(whfrag_kernel, dim3((983040+255)/256), dim3(256), 0, stream,
                     wps, whq);

  // --- pre-pack input-gate weights to bf16 pair-words [n][K/2], fwd|bwd fused
  hipLaunchKernelGGL(packB_kernel, dim3(256,24), dim3(256), 0, stream,
                     Wi0f, G3, bpk0, 16384);
  hipLaunchKernelGGL(packB_kernel, dim3(256,24), dim3(256), 0, stream,
                     Wi0b, G3, bpk0 + (size_t)1536*8192, 16384);
  for (int l=0;l<4;l++){
    unsigned int* d = bpkR + (size_t)l*3072*512;
    hipLaunchKernelGGL(packB_kernel, dim3(16,24), dim3(256), 0, stream,
                       WiRf + (size_t)l*1024*1536, G3, d, 1024);
    hipLaunchKernelGGL(packB_kernel, dim3(16,24), dim3(256), 0, stream,
                       WiRb + (size_t)l*1024*1536, G3, d + (size_t)1536*512, 1024);
  }

  // --- day transform + softsign -> bf16 hpadb rows 31..8222
  hipLaunchKernelGGL(day_gemm, dim3(64,4), dim3(256), 0, stream,
                     x, wtpk, bsel, hpadb);

  // --- layer 0 input gates: fused fwd+bwd, frame-gather bf16 A, 768 blocks
  hipLaunchKernelGGL(HIP_KERNEL_NAME(gemm_bt<64,1>), dim3(32,24), dim3(256), 0, stream,
                     hpadb, (const unsigned int*)nullptr, (const unsigned int*)nullptr,
                     bpk0, bi0f, bi0b, gi, 16384, GS);
  hipLaunchKernelGGL(scan2_kernel, dim3(32), dim3(512), 0, stream,
                     gi, whq, whq + (size_t)98304, bhn0f, bhn0b,
                     hbuf[0][0], hbuf[0][1], exch);

  // --- layers 1..4: fused fwd+bwd GEMM (N=3072), then scan
  for (int l=1;l<5;l++){
    hipLaunchKernelGGL(poison_kernel, dim3(1024), dim3(256), 0, stream,
                       exch, EXNW);
    hipLaunchKernelGGL(HIP_KERNEL_NAME(gemm_bt<128,2>), dim3(16,24), dim3(256), 0, stream,
                       (const unsigned short*)nullptr, hbuf[l-1][0], hbuf[l-1][1],
                       bpkR + (size_t)(l-1)*3072*512,
                       biRf + (l-1)*1536, biRb + (l-1)*1536, gi, 1024, GS);
    hipLaunchKernelGGL(scan2_kernel, dim3(32), dim3(512), 0, stream,
                       gi, whq + (size_t)(2*l)*98304, whq + (size_t)(2*l+1)*98304,
                       bhnRf + (l-1)*512, bhnRb + (l-1)*512,
                       hbuf[l][0], hbuf[l][1], exch);
  }

  // --- decoder + log_softmax
  hipLaunchKernelGGL(decoder_kernel, dim3(2048), dim3(64), 0, stream,
                     hbuf[4][0], hbuf[4][1], Wdec, bdec, out);
}

// Round 11
// 2267.780 us; speedup vs baseline: 1.7407x; 1.7407x over previous
//
#include <hip/hip_runtime.h>
#include <stdint.h>

// ---------------------------------------------------------------------------
// RNN speech decoder. R15:
//  * R14 post-mortem: j-split-16 doubled sync fan-in (7->15 partners) and
//    locked 32 blocks into one ring -> skew-dominated regression. Partner
//    count is a latency multiplier.
//  * R15 splits the M axis instead: 32 blocks = 2dir x 8j x 2mhalf. Chunks
//    are independent across the exchange, so each block needs only the 7
//    same-mhalf partner j-blocks: FOUR independent 8-block rings. Fan-in 7
//    (R13 statistics), per-wave MFMA 48->24, act 4->2 cols/thread, LDS
//    113->57KB. Slab word = 4B, indexed [dir][j][idx][mh*512 + ml*32+cw].
//  * Protocol byte-identical to R13 (poison payload, batched retry,
//    publish-first). GEMM stack / decoder / day path unchanged.
// ---------------------------------------------------------------------------

#define T_SEQ 2048
#define G3    1536
#define GS    3072   // fused gate width (fwd | bwd)
#define HW    256    // packed bf16 words per h vector
#define CLEN  64
#define WARM  64
#define NCH   32     // chunks per dir
#define NST   128    // steps per scan (CLEN+WARM)

typedef __attribute__((ext_vector_type(8))) short short8;
typedef __attribute__((ext_vector_type(4))) float f32x4;

__device__ inline unsigned int pack_bf16(float a, float b){
  unsigned int ua = __float_as_uint(a); ua = (ua + 0x7FFFu + ((ua>>16)&1u)) >> 16;
  unsigned int ub = __float_as_uint(b); ub = (ub + 0x7FFFu + ((ub>>16)&1u)) >> 16;
  return (ub<<16) | (ua & 0xFFFFu);
}
__device__ inline float bf2f(unsigned int h){ return __uint_as_float(h<<16); }

#define GBN 128
#define GBK 64
#define LSTR 36

// ---------------------------------------------------------------------------
// Day GEMM: C = softsign(x @ dayWT + bsel) -> bf16 hpadb rows 31..8222.
// ---------------------------------------------------------------------------
__global__ __launch_bounds__(256)
void day_gemm(const float* __restrict__ A, const unsigned int* __restrict__ Bpk,
              const float* __restrict__ bias, unsigned short* __restrict__ Cb)
{
  __shared__ __align__(16) unsigned int aL[128*LSTR];
  __shared__ __align__(16) unsigned int bL[GBN*LSTR];
  const int tid = threadIdx.x;
  const int m0 = blockIdx.x * 128;
  const int n0 = blockIdx.y * GBN;
  const int lane = tid & 63;
  const int w = tid >> 6;
  const int wm = (w & 1) * 64;
  const int wn = (w >> 1) * 64;
  const int ln = lane & 15;
  const int q  = lane >> 4;
  const int K = 512;

  f32x4 acc[4][4];
#pragma unroll
  for (int i=0;i<4;i++)
#pragma unroll
    for (int j=0;j<4;j++) acc[i][j] = (f32x4)0.f;

  const int ar = tid >> 1, ah = tid & 1;
  const int br = tid >> 1, bh = tid & 1;

  for (int kt = 0; kt < K/GBK; kt++){
    {
      const float* ap = A + (size_t)(m0+ar)*K + kt*GBK + ah*32;
      float4 av[8];
#pragma unroll
      for (int g=0; g<8; g++) av[g] = ((const float4*)ap)[g];
#pragma unroll
      for (int g=0; g<8; g++){
        aL[ar*LSTR + ah*16 + g*2    ] = pack_bf16(av[g].x, av[g].y);
        aL[ar*LSTR + ah*16 + g*2 + 1] = pack_bf16(av[g].z, av[g].w);
      }
    }
    {
      const unsigned int* bp = Bpk + (size_t)(n0+br)*(K>>1) + kt*32 + bh*16;
#pragma unroll
      for (int g=0; g<4; g++)
        *((uint4*)&bL[br*LSTR + bh*16 + g*4]) = ((const uint4*)bp)[g];
    }
    __syncthreads();
#pragma unroll
    for (int ks=0; ks<2; ks++){
      short8 af[4], bf[4];
#pragma unroll
      for (int i=0;i<4;i++){
        uint4 u = *(const uint4*)&aL[(wm + i*16 + ln)*LSTR + ks*16 + q*4];
        af[i] = *(const short8*)&u;
      }
#pragma unroll
      for (int j=0;j<4;j++){
        uint4 u = *(const uint4*)&bL[(wn + j*16 + ln)*LSTR + ks*16 + q*4];
        bf[j] = *(const short8*)&u;
      }
#pragma unroll
      for (int i=0;i<4;i++)
#pragma unroll
        for (int j=0;j<4;j++)
          acc[i][j] = __builtin_amdgcn_mfma_f32_16x16x32_bf16(af[i], bf[j], acc[i][j], 0,0,0);
    }
    __syncthreads();
  }
#pragma unroll
  for (int i=0;i<4;i++)
#pragma unroll
    for (int j=0;j<4;j++){
      int n = n0 + wn + j*16 + ln;
      float bs = bias[n];
#pragma unroll
      for (int r=0;r<4;r++){
        int m = m0 + wm + i*16 + q*4 + r;
        float v = acc[i][j][r] + bs;
        v = v / (1.f + fabsf(v));
        Cb[(size_t)(m+31)*512 + n] = (unsigned short)(pack_bf16(v, v) & 0xFFFFu);
      }
    }
}

// ---------------------------------------------------------------------------
// Input-gate GEMM, bf16 A (unchanged).
// ---------------------------------------------------------------------------
template<int BM, int AM>
__global__ __launch_bounds__(256)
void gemm_bt(const unsigned short* __restrict__ Abf,
             const unsigned int* __restrict__ A1, const unsigned int* __restrict__ A2,
             const unsigned int* __restrict__ Bpk,
             const float* __restrict__ biasF, const float* __restrict__ biasB,
             float* __restrict__ C, int K, int ldc)
{
  constexpr int AI = BM/32;
  __shared__ __align__(16) unsigned int aL[BM*LSTR];
  __shared__ __align__(16) unsigned int bL[GBN*LSTR];
  const int tid = threadIdx.x;
  const int m0 = blockIdx.x * BM;
  const int n0 = blockIdx.y * GBN;
  const int lane = tid & 63;
  const int w = tid >> 6;
  const int wm = (w & 1) * (BM/2);
  const int wn = (w >> 1) * 64;
  const int ln = lane & 15;
  const int q  = lane >> 4;

  f32x4 acc[AI][4];
#pragma unroll
  for (int i=0;i<AI;i++)
#pragma unroll
    for (int j=0;j<4;j++) acc[i][j] = (f32x4)0.f;

  const int ldKw = K >> 1;
  const int br = tid >> 1, bh = tid & 1;

  for (int kt = 0; kt < K/GBK; kt++){
    if (AM == 1){
      const int ar = tid >> 2, ah = tid & 3;
      const int row = (m0+ar)*4 + (kt>>3);
      const uint4* ap = (const uint4*)(Abf + (size_t)row*512 + (kt&7)*64 + ah*16);
      *((uint4*)&aL[ar*LSTR + ah*8    ]) = ap[0];
      *((uint4*)&aL[ar*LSTR + ah*8 + 4]) = ap[1];
    } else {
      const int ar = tid >> 1, ah = tid & 1;
      const int k0 = kt*GBK;
      const unsigned int* ub = ((k0 < 512) ? A1 : A2)
                               + (size_t)(m0+ar)*HW + ((k0 & 511) >> 1) + ah*16;
#pragma unroll
      for (int g=0; g<4; g++)
        *((uint4*)&aL[ar*LSTR + ah*16 + g*4]) = ((const uint4*)ub)[g];
    }
    {
      const unsigned int* bp = Bpk + (size_t)(n0+br)*ldKw + kt*32 + bh*16;
#pragma unroll
      for (int g=0; g<4; g++)
        *((uint4*)&bL[br*LSTR + bh*16 + g*4]) = ((const uint4*)bp)[g];
    }
    __syncthreads();
#pragma unroll
    for (int ks=0; ks<2; ks++){
      short8 af[AI], bf[4];
#pragma unroll
      for (int i=0;i<AI;i++){
        uint4 u = *(const uint4*)&aL[(wm + i*16 + ln)*LSTR + ks*16 + q*4];
        af[i] = *(const short8*)&u;
      }
#pragma unroll
      for (int j=0;j<4;j++){
        uint4 u = *(const uint4*)&bL[(wn + j*16 + ln)*LSTR + ks*16 + q*4];
        bf[j] = *(const short8*)&u;
      }
#pragma unroll
      for (int i=0;i<AI;i++)
#pragma unroll
        for (int j=0;j<4;j++)
          acc[i][j] = __builtin_amdgcn_mfma_f32_16x16x32_bf16(af[i], bf[j], acc[i][j], 0,0,0);
    }
    __syncthreads();
  }
#pragma unroll
  for (int i=0;i<AI;i++)
#pragma unroll
    for (int j=0;j<4;j++){
      int n = n0 + wn + j*16 + ln;
      float bs = (n < 1536) ? biasF[n] : biasB[n-1536];
#pragma unroll
      for (int r=0;r<4;r++){
        int m = m0 + wm + i*16 + q*4 + r;
        C[(size_t)m*ldc + n] = acc[i][j][r] + bs;
      }
    }
}

// ---------------------------------------------------------------------------
// scan2 (R15): M-batched MFMA GRU scan, M-split, poison sync, batched retry.
// Grid 32 x 512thr. dir=bid&1, j=(bid>>1)&7, mh=bid>>4 (chunk half).
// Block owns chunks mh*16..+15, cols [64j,64j+64). Four independent rings
// of 8 blocks (dir x mh); fan-in 7. Slab (dir,j,idx): 1024 u32; word
// wi = m*32+cw packs cols j*64+2cw of chunk m. Per step:
//   [gi prefetch] [poll 7 partner u32 (batched retry) -> hA[p]] [B1]
//   [MFMA M=16: 24/wave] [B2] [act 2 cols; publish-first].
// ---------------------------------------------------------------------------
__global__ __launch_bounds__(512)
void scan2_kernel(const float* __restrict__ gi,
                  const uint4* __restrict__ wqF, const uint4* __restrict__ wqB,
                  const float* __restrict__ bhnF, const float* __restrict__ bhnB,
                  unsigned int* __restrict__ hbF, unsigned int* __restrict__ hbB,
                  unsigned int* __restrict__ exch)
{
  const int bid = blockIdx.x;
  const int dir = bid & 1;
  const int j   = (bid >> 1) & 7;
  const int mh  = bid >> 4;          // chunk half 0/1
  const int tid = threadIdx.x;
  const int w    = tid >> 6;
  const int lane = tid & 63;
  const int ln = lane & 15, q = lane >> 4;
  const int kt = w >> 2, wn = w & 3;
  const unsigned int POI = 0xAAAAAAAAu;

  const float* gi_d = gi + dir*1536;
  const uint4* wq = dir ? wqB : wqF;
  const float* bhn = dir ? bhnB : bhnF;
  unsigned int* hb = dir ? hbB : hbF;
  unsigned int* exd = exch + (size_t)dir*8*NST*1024;

  // ---- weights: 24 frags/lane (3 nt x 8 kk-local), R13 layout
  short8 w8[3][8];
  {
    const uint4* wb = wq + (size_t)j*12*16*64;
#pragma unroll
    for (int nt=0; nt<3; nt++)
#pragma unroll
      for (int kkl=0; kkl<8; kkl++){
        uint4 u = wb[(size_t)(((wn*3+nt)*16) + (kt*8+kkl))*64 + lane];
        w8[nt][kkl] = *(const short8*)&u;
      }
  }

  __shared__ __align__(16) unsigned short hA[2][16][512];
  __shared__ __align__(16) float gL[2][16][196];

  const int ml = tid >> 5;   // local chunk 0..15
  const int cw = tid & 31;   // col-word (2 cols)
  const int c0 = 2*cw;
  const int m  = mh*16 + ml; // absolute chunk
  float2 bh2 = *(const float2*)&bhn[j*64 + c0];
  float hp0=0.f, hp1=0.f;

  {
    uint4 zz; zz.x=0u; zz.y=0u; zz.z=0u; zz.w=0u;
    uint4* zp = (uint4*)&hA[0][0][0];
    for (int i2 = tid; i2 < 2048; i2 += 512) zp[i2] = zz;
  }
  __syncthreads();

  for (int idx = 0; idx < NST; idx++){
    const int p = idx & 1;
    // gi prefetch (validity-clamped address)
    int t = dir ? (64*m + 127 - idx) : (64*m - 64 + idx);
    const bool valid = (t >= 0) && (t < T_SEQ);
    int tc = t < 0 ? 0 : (t > T_SEQ-1 ? T_SEQ-1 : t);
    const float* gb = gi_d + (size_t)tc*GS + j*64 + c0;
    float2 g_r = *(const float2*)(gb);
    float2 g_z = *(const float2*)(gb + 512);
    float2 g_n = *(const float2*)(gb + 1024);

    if (idx > 0){
      // initial batch: 7 loads in flight (poison-in-payload)
      unsigned int v[7];
#pragma unroll
      for (int rb = 0; rb < 7; rb++){
        int jp = (j + 1 + rb) & 7;
        v[rb] = __hip_atomic_load(
            &exd[((size_t)jp*NST + (idx-1))*1024 + mh*512 + tid],
            __ATOMIC_RELAXED, __HIP_MEMORY_SCOPE_AGENT);
      }
      // batched retry (R13): reload ALL 7 per round, then merge misses
      for (;;){
        bool bad = false;
#pragma unroll
        for (int rb = 0; rb < 7; rb++)
          if (v[rb] == POI) bad = true;
        if (!bad) break;
        unsigned int nv[7];
#pragma unroll
        for (int rb = 0; rb < 7; rb++){
          int jp = (j + 1 + rb) & 7;
          nv[rb] = __hip_atomic_load(
              &exd[((size_t)jp*NST + (idx-1))*1024 + mh*512 + tid],
              __ATOMIC_RELAXED, __HIP_MEMORY_SCOPE_AGENT);
        }
#pragma unroll
        for (int rb = 0; rb < 7; rb++)
          if (v[rb] == POI) v[rb] = nv[rb];
      }
#pragma unroll
      for (int rb = 0; rb < 7; rb++){
        int jp = (j + 1 + rb) & 7;
        int uo = (ml*512 + jp*64 + c0) ^ ((ml&7)<<3);
        ((unsigned int*)&hA[p][0][0])[uo>>1] = v[rb];
      }
    }
    __syncthreads();                       // B1

    // ---- MFMA: H[16x512] @ WhT-slice, K-half kt, 24 MFMA/wave
    f32x4 ac[3];
#pragma unroll
    for (int nt=0; nt<3; nt++) ac[nt] = (f32x4)0.f;
    const unsigned short* hbp = &hA[p][0][0];
#pragma unroll
    for (int kkl=0; kkl<8; kkl++){
      int kb = (kt*8 + kkl)*32 + q*8;
      int ua = (ln*512 + kb) ^ ((ln&7)<<3);
      short8 af = *(const short8*)&hbp[ua];
#pragma unroll
      for (int nt=0; nt<3; nt++)
        ac[nt] = __builtin_amdgcn_mfma_f32_16x16x32_bf16(af, w8[nt][kkl], ac[nt], 0,0,0);
    }
#pragma unroll
    for (int nt=0; nt<3; nt++){
      int ncol = (wn*3+nt)*16 + ln;
      float* gw = &gL[kt][0][0];
#pragma unroll
      for (int r=0; r<4; r++)
        gw[(4*q + r)*196 + ncol] = ac[nt][r];
    }
    __syncthreads();                       // B2

    // ---- activation: thread = (local chunk ml, cols c0..c0+1)
    const float* g0 = &gL[0][ml][0];
    const float* g1 = &gL[1][ml][0];
    float2 xr0 = *(const float2*)&g0[c0],     xr1 = *(const float2*)&g1[c0];
    float2 xz0 = *(const float2*)&g0[64+c0],  xz1 = *(const float2*)&g1[64+c0];
    float2 xn0 = *(const float2*)&g0[128+c0], xn1 = *(const float2*)&g1[128+c0];

    float h0,h1;
    {
      float ar = xr0.x + xr1.x, az = xz0.x + xz1.x, an = xn0.x + xn1.x;
      float r = __fdividef(1.f, 1.f + __expf(-(g_r.x + ar)));
      float z = __fdividef(1.f, 1.f + __expf(-(g_z.x + az)));
      float e = __expf(2.f*(g_n.x + r*(an + bh2.x)));
      float n = 1.f - __fdividef(2.f, e + 1.f);
      h0 = (1.f - z)*n + z*hp0; h0 = valid ? h0 : 0.f; hp0 = h0;
    }
    {
      float ar = xr0.y + xr1.y, az = xz0.y + xz1.y, an = xn0.y + xn1.y;
      float r = __fdividef(1.f, 1.f + __expf(-(g_r.y + ar)));
      float z = __fdividef(1.f, 1.f + __expf(-(g_z.y + az)));
      float e = __expf(2.f*(g_n.y + r*(an + bh2.y)));
      float n = 1.f - __fdividef(2.f, e + 1.f);
      h1 = (1.f - z)*n + z*hp1; h1 = valid ? h1 : 0.f; hp1 = h1;
    }

    unsigned int pv = pack_bf16(h0, h1);
    if (pv == POI) pv ^= 1u;               // poison collision: 1-ulp flip
    // publish FIRST (earliest L3 visibility), then local LDS + hb
    __hip_atomic_store(&exd[((size_t)j*NST + idx)*1024 + mh*512 + tid], pv,
                       __ATOMIC_RELAXED, __HIP_MEMORY_SCOPE_AGENT);
    int uo = (ml*512 + j*64 + c0) ^ ((ml&7)<<3);
    ((unsigned int*)&hA[p^1][0][0])[uo>>1] = pv;
    if (idx >= WARM)
      hb[(size_t)t*HW + j*32 + cw] = pv;
    // no 3rd barrier: parity dbuf keeps LDS writes disjoint (see R9).
  }
}

// ---------------------------------------------------------------------------
// Decoder: logits = [hf|hb](packed bf16) @ Wdec + bdec, row log_softmax.
// ---------------------------------------------------------------------------
__global__ __launch_bounds__(64)
void decoder_kernel(const unsigned int* __restrict__ hf, const unsigned int* __restrict__ hbk,
                    const float* __restrict__ Wd, const float* __restrict__ bd,
                    float* __restrict__ out)
{
  const int t = blockIdx.x;
  const int lane = threadIdx.x;
  __shared__ float y[1024];
  for (int i = lane; i < HW; i += 64){
    unsigned int uf = hf [(size_t)t*HW + i];
    unsigned int ub = hbk[(size_t)t*HW + i];
    y[2*i]       = bf2f(uf & 0xFFFFu); y[2*i+1]       = bf2f(uf >> 16);
    y[512 + 2*i] = bf2f(ub & 0xFFFFu); y[512 + 2*i+1] = bf2f(ub >> 16);
  }
  __syncthreads();
  float v = -1e30f;
  if (lane < 41){
    float acc = bd[lane];
    for (int k=0;k<1024;k++) acc += y[k] * Wd[(size_t)k*41 + lane];
    v = acc;
  }
  float m = v;
#pragma unroll
  for (int off=32; off; off>>=1) m = fmaxf(m, __shfl_xor(m, off, 64));
  float e = (lane < 41) ? __expf(v - m) : 0.f;
  float ssum = e;
#pragma unroll
  for (int off=32; off; off>>=1) ssum += __shfl_xor(ssum, off, 64);
  if (lane < 41) out[(size_t)t*41 + lane] = (v - m) - __logf(ssum);
}

// ---------------------------------------------------------------------------
// Prep kernels
// ---------------------------------------------------------------------------
__global__ void poison_kernel(unsigned int* p, long n){
  long i = (long)blockIdx.x*blockDim.x + threadIdx.x;
  long st = (long)gridDim.x*blockDim.x;
  for (; i < n; i += st) p[i] = 0xAAAAAAAAu;
}
__global__ void zero_u_kernel(unsigned int* p, int n){
  int i = blockIdx.x*blockDim.x + threadIdx.x;
  if (i < n) p[i] = 0u;
}
// day weights: packed word[n][k2] = pack(dayW[d][n][2k2], dayW[d][n][2k2+1])
__global__ void daysel_kernel(const float* __restrict__ dw, const float* __restrict__ db,
                              const int* __restrict__ didx, unsigned int* __restrict__ wtpk,
                              float* __restrict__ bsel){
  int d = *didx;
  int i = blockIdx.x*256 + threadIdx.x;
  if (i < 512*256){
    int n = i >> 8, k2 = i & 255;
    const float* s = dw + (size_t)d*262144 + (size_t)n*512 + 2*k2;
    wtpk[i] = pack_bf16(s[0], s[1]);
  }
  if (i < 512) bsel[i] = db[(size_t)d*512 + i];
}
// Transpose-pack fp32 B [K][ldb] column slice -> pair-words dst[n][K/2].
__global__ __launch_bounds__(256)
void packB_kernel(const float* __restrict__ src, int ldb,
                  unsigned int* __restrict__ dst, int K)
{
  __shared__ float tile[64][65];
  const int k0 = blockIdx.x * 64;
  const int n0 = blockIdx.y * 64;
  const int tid = threadIdx.x;
#pragma unroll
  for (int g=0; g<16; g++){
    int idx = g*256 + tid;
    int kr = idx >> 6, nc = idx & 63;
    tile[kr][nc] = src[(size_t)(k0+kr)*ldb + n0 + nc];
  }
  __syncthreads();
  const int ldKw = K >> 1;
#pragma unroll
  for (int g=0; g<8; g++){
    int wi = g*256 + tid;
    int nl = wi >> 5, k2 = wi & 31;
    dst[(size_t)(n0+nl)*ldKw + (k0>>1) + k2] = pack_bf16(tile[2*k2][nl], tile[2*k2+1][nl]);
  }
}
// Wh frag-pack for scan2 (R13/R8 layout, j=8).
struct WhPtrs { const float* p[10]; };
__global__ void whfrag_kernel(WhPtrs wps, uint4* __restrict__ dst){
  int i = blockIdx.x*256 + threadIdx.x;
  if (i >= 983040) return;
  int lane = i & 63;
  int r1 = i >> 6;
  int kk = r1 & 15;
  int r2 = r1 >> 4;
  int nt = r2 % 12;
  int r3 = r2 / 12;
  int j  = r3 & 7;
  int ld = r3 >> 3;
  int nl = nt*16 + (lane & 15);
  int sec = nl >> 6, off = nl & 63;
  int gcol = sec*512 + j*64 + off;
  int kb = kk*32 + (lane >> 4)*8;
  const float* W = wps.p[ld];
  unsigned int wd[4];
#pragma unroll
  for (int wq2=0; wq2<4; wq2++)
    wd[wq2] = pack_bf16(W[(size_t)(kb + 2*wq2)*G3 + gcol],
                        W[(size_t)(kb + 2*wq2 + 1)*G3 + gcol]);
  uint4 o; o.x = wd[0]; o.y = wd[1]; o.z = wd[2]; o.w = wd[3];
  dst[i] = o;
}

// ---------------------------------------------------------------------------
extern "C" void kernel_launch(void* const* d_in, const int* in_sizes, int n_in,
                              void* d_out, int out_size, void* d_ws, size_t ws_size,
                              hipStream_t stream)
{
  const float* x     = (const float*)d_in[0];
  const int*   didx  = (const int*)  d_in[1];
  const float* dayW  = (const float*)d_in[2];
  const float* dayB  = (const float*)d_in[3];
  const float* Wi0f  = (const float*)d_in[4];
  const float* bi0f  = (const float*)d_in[5];
  const float* Wh0f  = (const float*)d_in[6];
  const float* bhn0f = (const float*)d_in[7];
  const float* Wi0b  = (const float*)d_in[8];
  const float* bi0b  = (const float*)d_in[9];
  const float* Wh0b  = (const float*)d_in[10];
  const float* bhn0b = (const float*)d_in[11];
  const float* WiRf  = (const float*)d_in[12];
  const float* biRf  = (const float*)d_in[13];
  const float* WhRf  = (const float*)d_in[14];
  const float* bhnRf = (const float*)d_in[15];
  const float* WiRb  = (const float*)d_in[16];
  const float* biRb  = (const float*)d_in[17];
  const float* WhRb  = (const float*)d_in[18];
  const float* bhnRb = (const float*)d_in[19];
  const float* Wdec  = (const float*)d_in[20];
  const float* bdec  = (const float*)d_in[21];
  float* out = (float*)d_out;

  char* ws = (char*)d_ws;
  size_t off = 0;
  unsigned int* hbuf[5][2];
  for (int l=0;l<5;l++) for (int d=0;d<2;d++){
    hbuf[l][d] = (unsigned int*)(ws+off); off += (size_t)T_SEQ*HW*4;
  }
  float* gi   = (float*)(ws+off); off += (size_t)T_SEQ*GS*4;             // 25.2 MB
  unsigned short* hpadb = (unsigned short*)(ws+off); off += ((size_t)8223*512*2 + 255) & ~255ull;
  unsigned int* wtpk = (unsigned int*)(ws+off); off += (size_t)512*256*4;
  float* bsel = (float*)(ws+off); off += 2048;
  uint4* whq = (uint4*)(ws+off); off += (size_t)983040*16;               // 15.7 MB
  unsigned int* exch = (unsigned int*)(ws+off); off += (size_t)2*8*NST*1024*4;  // 8.4 MB
  unsigned int* bpk0 = (unsigned int*)(ws+off); off += (size_t)3072*8192*4;   // 100.7 MB
  unsigned int* bpkR = (unsigned int*)(ws+off); off += (size_t)4*3072*512*4;  // 25.2 MB
  // total ~204 MB

  const long EXNW = (long)2*8*NST*1024;   // exch in u32 words

  // --- prep
  hipLaunchKernelGGL(poison_kernel, dim3(1024), dim3(256), 0, stream,
                     exch, EXNW);
  hipLaunchKernelGGL(zero_u_kernel, dim3((7936+255)/256), dim3(256), 0, stream,
                     (unsigned int*)hpadb, 7936);  // rows 0..30 bf16 zeros
  hipLaunchKernelGGL(daysel_kernel, dim3(512), dim3(256), 0, stream,
                     dayW, dayB, didx, wtpk, bsel);
  WhPtrs wps;
  wps.p[0] = Wh0f; wps.p[1] = Wh0b;
  for (int l=0;l<4;l++){
    wps.p[2+2*l] = WhRf + (size_t)l*512*1536;
    wps.p[3+2*l] = WhRb + (size_t)l*512*1536;
  }
  hipLaunchKernelGGL(whfrag_kernel, dim3((983040+255)/256), dim3(256), 0, stream,
                     wps, whq);

  // --- pre-pack input-gate weights to bf16 pair-words [n][K/2], fwd|bwd fused
  hipLaunchKernelGGL(packB_kernel, dim3(256,24), dim3(256), 0, stream,
                     Wi0f, G3, bpk0, 16384);
  hipLaunchKernelGGL(packB_kernel, dim3(256,24), dim3(256), 0, stream,
                     Wi0b, G3, bpk0 + (size_t)1536*8192, 16384);
  for (int l=0;l<4;l++){
    unsigned int* d = bpkR + (size_t)l*3072*512;
    hipLaunchKernelGGL(packB_kernel, dim3(16,24), dim3(256), 0, stream,
                       WiRf + (size_t)l*1024*1536, G3, d, 1024);
    hipLaunchKernelGGL(packB_kernel, dim3(16,24), dim3(256), 0, stream,
                       WiRb + (size_t)l*1024*1536, G3, d + (size_t)1536*512, 1024);
  }

  // --- day transform + softsign -> bf16 hpadb rows 31..8222
  hipLaunchKernelGGL(day_gemm, dim3(64,4), dim3(256), 0, stream,
                     x, wtpk, bsel, hpadb);

  // --- layer 0 input gates: fused fwd+bwd, frame-gather bf16 A, 768 blocks
  hipLaunchKernelGGL(HIP_KERNEL_NAME(gemm_bt<64,1>), dim3(32,24), dim3(256), 0, stream,
                     hpadb, (const unsigned int*)nullptr, (const unsigned int*)nullptr,
                     bpk0, bi0f, bi0b, gi, 16384, GS);
  hipLaunchKernelGGL(scan2_kernel, dim3(32), dim3(512), 0, stream,
                     gi, whq, whq + (size_t)98304, bhn0f, bhn0b,
                     hbuf[0][0], hbuf[0][1], exch);

  // --- layers 1..4: fused fwd+bwd GEMM (N=3072), then scan
  for (int l=1;l<5;l++){
    hipLaunchKernelGGL(poison_kernel, dim3(1024), dim3(256), 0, stream,
                       exch, EXNW);
    hipLaunchKernelGGL(HIP_KERNEL_NAME(gemm_bt<128,2>), dim3(16,24), dim3(256), 0, stream,
                       (const unsigned short*)nullptr, hbuf[l-1][0], hbuf[l-1][1],
                       bpkR + (size_t)(l-1)*3072*512,
                       biRf + (l-1)*1536, biRb + (l-1)*1536, gi, 1024, GS);
    hipLaunchKernelGGL(scan2_kernel, dim3(32), dim3(512), 0, stream,
                       gi, whq + (size_t)(2*l)*98304, whq + (size_t)(2*l+1)*98304,
                       bhnRf + (l-1)*512, bhnRb + (l-1)*512,
                       hbuf[l][0], hbuf[l][1], exch);
  }

  // --- decoder + log_softmax
  hipLaunchKernelGGL(decoder_kernel, dim3(2048), dim3(64), 0, stream,
                     hbuf[4][0], hbuf[4][1], Wdec, bdec, out);
}